// Round 3
// baseline (15760.823 us; speedup 1.0000x reference)
//
#include <hip/hip_runtime.h>

// Problem constants
#define BB   64      // batch
#define TT   256     // seq len
#define II   768     // input dim
#define HH   384     // hidden per direction
#define DD   768     // 2*HH
#define G3   1152    // 3*HH
#define G6   2304    // both directions' gates

#define TILE 128
#define BK   16

typedef unsigned long long u64t;

// ---------------------------------------------------------------------------
// GEMM: gxT[t][n][b] = bias[n] + sum_k X[t,b,k] * W[n,k]   (n in [0,2304))
// OUTPUT IS TRANSPOSED (n-major, batch-minor) so the recurrent kernel reads
// coalesced 256-B rows and no gx cache line straddles XCDs.
// xmode 0: X = Sentences [B][T][768]; xmode 1: X = [T*B][768] row-major.
// ---------------------------------------------------------------------------
__global__ __launch_bounds__(256) void gemm_gx(
    const float* __restrict__ X, int xmode,
    const float* __restrict__ wf, const float* __restrict__ wb,
    const float* __restrict__ bif, const float* __restrict__ bib,
    float* __restrict__ gx)
{
    __shared__ float As[BK][TILE + 4];
    __shared__ float Bs[BK][TILE + 4];
    const int tid = threadIdx.x;
    const int tx = tid & 15, ty = tid >> 4;
    const int m0 = blockIdx.y * TILE;
    const int n0 = blockIdx.x * TILE;

    float acc[8][8];
#pragma unroll
    for (int i = 0; i < 8; i++)
#pragma unroll
        for (int j = 0; j < 8; j++) acc[i][j] = 0.f;

    for (int k0 = 0; k0 < 768; k0 += BK) {
#pragma unroll
        for (int l = 0; l < 2; l++) {
            int id = tid + l * 256;          // 0..511
            int r  = id >> 2;                // 0..127
            int kq = (id & 3) * 4;
            int m  = m0 + r;
            const float* src;
            if (xmode == 0) {
                int b = m & 63, t = m >> 6;
                src = X + (size_t)b * (TT * II) + (size_t)t * II + k0 + kq;
            } else {
                src = X + (size_t)m * 768 + k0 + kq;
            }
            float4 v = *(const float4*)src;
            As[kq + 0][r] = v.x; As[kq + 1][r] = v.y;
            As[kq + 2][r] = v.z; As[kq + 3][r] = v.w;
        }
#pragma unroll
        for (int l = 0; l < 2; l++) {
            int id = tid + l * 256;
            int r  = id >> 2;
            int kq = (id & 3) * 4;
            int n  = n0 + r;
            const float* wsrc = (n < G3) ? (wf + (size_t)n * 768)
                                         : (wb + (size_t)(n - G3) * 768);
            float4 v = *(const float4*)(wsrc + k0 + kq);
            Bs[kq + 0][r] = v.x; Bs[kq + 1][r] = v.y;
            Bs[kq + 2][r] = v.z; Bs[kq + 3][r] = v.w;
        }
        __syncthreads();
#pragma unroll
        for (int kk = 0; kk < BK; ++kk) {
            float av[8], bv[8];
            *(float4*)&av[0] = *(const float4*)&As[kk][ty * 8];
            *(float4*)&av[4] = *(const float4*)&As[kk][ty * 8 + 4];
            *(float4*)&bv[0] = *(const float4*)&Bs[kk][tx * 8];
            *(float4*)&bv[4] = *(const float4*)&Bs[kk][tx * 8 + 4];
#pragma unroll
            for (int i = 0; i < 8; i++)
#pragma unroll
                for (int j = 0; j < 8; j++)
                    acc[i][j] = fmaf(av[i], bv[j], acc[i][j]);
        }
        __syncthreads();
    }

    // transposed write: gxT[t][n][b]. A 64-B line (16 b-values of one n) is
    // filled by threads of this same WG -> L2 assembles full lines.
#pragma unroll
    for (int i = 0; i < 8; i++) {
        int m = m0 + ty * 8 + i;
        int t = m >> 6, b = m & 63;
        float* dst = gx + ((size_t)t * G6 + n0 + tx * 8) * 64 + b;
#pragma unroll
        for (int j = 0; j < 8; j++) {
            int n = n0 + tx * 8 + j;
            float bias = (n < G3) ? bif[n] : bib[n - G3];
            dst[(size_t)j * 64] = acc[i][j] + bias;
        }
    }
}

// ---------------------------------------------------------------------------
// Recurrent kernel v3. 256 WGs x 256 threads (1 per CU), hand-rolled
// hierarchical flush-free barrier, direction-clustered XCD mapping.
//
// Mapping (perf-only; correctness holds for any placement since all h
// exchange is agent-scope): xcd = bid&7; dir = xcd>>2; each XCD owns 96
// contiguous columns of one direction. WG owns 3 columns; wave w in 0..3
// covers k-chunk [w*96,(w+1)*96) for all 9 (col,gate) dots; partials
// reduced through LDS; wave w<3 finalizes column c0+w.
//
// h ping-pong in global, interleaved [k/4][b][4] fp32, exchanged via
// agent-scope relaxed atomics (L3-coherent, no L2 flush). gx read in
// transposed [t][n][b] layout (coalesced, issued at step top, used last).
// ---------------------------------------------------------------------------
__global__ __launch_bounds__(256) void recur3(
    const float* __restrict__ gxT,  // [T][2304][64] (b_ih already added)
    const float* __restrict__ whf, const float* __restrict__ whb,
    const float* __restrict__ bhf, const float* __restrict__ bhb,
    float* __restrict__ hbuf,       // [2 dir][2 pp][96][64][4] floats, zeroed
    float* __restrict__ out,        // [T][B][768]
    unsigned* __restrict__ bar)     // [16]: [dir*4+xsl] arrivals, [8+dir] root
{
    extern __shared__ __align__(16) float smem[];
    float4* hs4 = (float4*)smem;            // 96*64 float4 = 98304 B
    float*  part = smem + 4 * 96 * 64;      // 4*9*64 floats = 9216 B

    const int bid = blockIdx.x;             // 0..255
    const int xcd = bid & 7;                // presumed XCD slot
    const int dir = xcd >> 2;               // 0: fwd (xcd 0-3), 1: bwd
    const int xsl = xcd & 3;
    const int idx = bid >> 3;               // 0..31
    const int c0  = (xsl * 32 + idx) * 3;   // 3 columns per WG, 96/XCD contiguous
    const int tid = threadIdx.x;
    const int lane = tid & 63;              // batch
    const int w   = __builtin_amdgcn_readfirstlane(tid >> 6);   // wave 0..3

    const float* wh = dir ? whb : whf;
    const float* bh = dir ? bhb : bhf;

    // 9 wave-uniform weight pointers, offset to this wave's k-chunk
    const float* wp[3][3];
#pragma unroll
    for (int col = 0; col < 3; col++)
#pragma unroll
        for (int g = 0; g < 3; g++)
            wp[col][g] = wh + (size_t)(g * HH + c0 + col) * HH + w * 96;

    const int c = c0 + w;                   // my column (valid for w<3)
    float bhr = 0.f, bhz = 0.f, bhn = 0.f;
    if (w < 3) { bhr = bh[c]; bhz = bh[HH + c]; bhn = bh[2 * HH + c]; }

    float* hpp = hbuf + (size_t)dir * 2 * (96 * 64 * 4);
    unsigned* cntx = bar + dir * 4 + xsl;
    unsigned* root = bar + 8 + dir;

    float hprev = 0.f;

    for (int s = 0; s < TT; s++) {
        const int t = dir ? (TT - 1 - s) : s;
        const float* hcur = hpp + (size_t)(s & 1) * (96 * 64 * 4);
        float*       hnxt = hpp + (size_t)((s & 1) ^ 1) * (96 * 64 * 4);

        // gx loads: independent of h, issue first, consumed last
        float gr = 0.f, gz = 0.f, gn = 0.f;
        if (w < 3) {
            const float* g0 = gxT + ((size_t)t * G6 + dir * G3) * 64;
            gr = g0[(size_t)(0 * HH + c) * 64 + lane];
            gz = g0[(size_t)(1 * HH + c) * 64 + lane];
            gn = g0[(size_t)(2 * HH + c) * 64 + lane];
        }

        // stage full h (96 KB) into LDS: 48 u64 per thread, linear copy,
        // agent-scope relaxed loads (L3-coherent, no flush)
        {
            const u64t* src = (const u64t*)hcur;
            u64t* dstl = (u64t*)hs4;
#pragma unroll 8
            for (int l = 0; l < 48; l++) {
                dstl[tid + l * 256] =
                    __hip_atomic_load(src + tid + l * 256,
                                      __ATOMIC_RELAXED, __HIP_MEMORY_SCOPE_AGENT);
            }
        }
        __syncthreads();

        // 9 partial dots over this wave's k-chunk (24 float4 groups)
        float a00 = 0.f, a01 = 0.f, a02 = 0.f;
        float a10 = 0.f, a11 = 0.f, a12 = 0.f;
        float a20 = 0.f, a21 = 0.f, a22 = 0.f;
        const int kb = w * 24;
#pragma unroll 2
        for (int kc = 0; kc < 24; kc++) {
            float4 hv = hs4[(size_t)(kb + kc) * 64 + lane];
            float4 v;
            v = *(const float4*)(wp[0][0] + kc * 4);
            a00 = fmaf(hv.x, v.x, a00); a00 = fmaf(hv.y, v.y, a00);
            a00 = fmaf(hv.z, v.z, a00); a00 = fmaf(hv.w, v.w, a00);
            v = *(const float4*)(wp[0][1] + kc * 4);
            a01 = fmaf(hv.x, v.x, a01); a01 = fmaf(hv.y, v.y, a01);
            a01 = fmaf(hv.z, v.z, a01); a01 = fmaf(hv.w, v.w, a01);
            v = *(const float4*)(wp[0][2] + kc * 4);
            a02 = fmaf(hv.x, v.x, a02); a02 = fmaf(hv.y, v.y, a02);
            a02 = fmaf(hv.z, v.z, a02); a02 = fmaf(hv.w, v.w, a02);
            v = *(const float4*)(wp[1][0] + kc * 4);
            a10 = fmaf(hv.x, v.x, a10); a10 = fmaf(hv.y, v.y, a10);
            a10 = fmaf(hv.z, v.z, a10); a10 = fmaf(hv.w, v.w, a10);
            v = *(const float4*)(wp[1][1] + kc * 4);
            a11 = fmaf(hv.x, v.x, a11); a11 = fmaf(hv.y, v.y, a11);
            a11 = fmaf(hv.z, v.z, a11); a11 = fmaf(hv.w, v.w, a11);
            v = *(const float4*)(wp[1][2] + kc * 4);
            a12 = fmaf(hv.x, v.x, a12); a12 = fmaf(hv.y, v.y, a12);
            a12 = fmaf(hv.z, v.z, a12); a12 = fmaf(hv.w, v.w, a12);
            v = *(const float4*)(wp[2][0] + kc * 4);
            a20 = fmaf(hv.x, v.x, a20); a20 = fmaf(hv.y, v.y, a20);
            a20 = fmaf(hv.z, v.z, a20); a20 = fmaf(hv.w, v.w, a20);
            v = *(const float4*)(wp[2][1] + kc * 4);
            a21 = fmaf(hv.x, v.x, a21); a21 = fmaf(hv.y, v.y, a21);
            a21 = fmaf(hv.z, v.z, a21); a21 = fmaf(hv.w, v.w, a21);
            v = *(const float4*)(wp[2][2] + kc * 4);
            a22 = fmaf(hv.x, v.x, a22); a22 = fmaf(hv.y, v.y, a22);
            a22 = fmaf(hv.z, v.z, a22); a22 = fmaf(hv.w, v.w, a22);
        }

        // write partials: part[w][col*3+g][lane]
        part[(size_t)(w * 9 + 0) * 64 + lane] = a00;
        part[(size_t)(w * 9 + 1) * 64 + lane] = a01;
        part[(size_t)(w * 9 + 2) * 64 + lane] = a02;
        part[(size_t)(w * 9 + 3) * 64 + lane] = a10;
        part[(size_t)(w * 9 + 4) * 64 + lane] = a11;
        part[(size_t)(w * 9 + 5) * 64 + lane] = a12;
        part[(size_t)(w * 9 + 6) * 64 + lane] = a20;
        part[(size_t)(w * 9 + 7) * 64 + lane] = a21;
        part[(size_t)(w * 9 + 8) * 64 + lane] = a22;
        __syncthreads();

        if (w < 3) {
            const int d0 = w * 3;
            float ar = part[(size_t)(0 * 9 + d0 + 0) * 64 + lane]
                     + part[(size_t)(1 * 9 + d0 + 0) * 64 + lane]
                     + part[(size_t)(2 * 9 + d0 + 0) * 64 + lane]
                     + part[(size_t)(3 * 9 + d0 + 0) * 64 + lane];
            float az = part[(size_t)(0 * 9 + d0 + 1) * 64 + lane]
                     + part[(size_t)(1 * 9 + d0 + 1) * 64 + lane]
                     + part[(size_t)(2 * 9 + d0 + 1) * 64 + lane]
                     + part[(size_t)(3 * 9 + d0 + 1) * 64 + lane];
            float an = part[(size_t)(0 * 9 + d0 + 2) * 64 + lane]
                     + part[(size_t)(1 * 9 + d0 + 2) * 64 + lane]
                     + part[(size_t)(2 * 9 + d0 + 2) * 64 + lane]
                     + part[(size_t)(3 * 9 + d0 + 2) * 64 + lane];

            float ghr = ar + bhr, ghz = az + bhz, ghn = an + bhn;
            float r  = 1.f / (1.f + expf(-(gr + ghr)));
            float z  = 1.f / (1.f + expf(-(gz + ghz)));
            float nn = tanhf(gn + r * ghn);
            float hnew = (1.f - z) * nn + z * hprev;
            hprev = hnew;                   // own column: keep in register

            // publish at agent scope (L3-visible, no flush)
            __hip_atomic_store(hnxt + (size_t)((c >> 2) * 64 + lane) * 4 + (c & 3),
                               hnew, __ATOMIC_RELAXED, __HIP_MEMORY_SCOPE_AGENT);
            // big output tensor: normal store (flushed at kernel end)
            out[(size_t)t * (BB * DD) + (size_t)lane * DD + dir * HH + c] = hnew;
        }

        if (s < TT - 1) {
            // hierarchical flush-free barrier per direction:
            // syncthreads drains all waves' vmem (h publish committed), then
            // tid0 arrives at the per-XCD counter; the 32nd arrival bumps the
            // root; everyone spins on root (4 increments per step).
            __syncthreads();
            if (tid == 0) {
                unsigned old = __hip_atomic_fetch_add(cntx, 1u, __ATOMIC_RELAXED,
                                                      __HIP_MEMORY_SCOPE_AGENT);
                if (old == 32u * (unsigned)(s + 1) - 1u)
                    __hip_atomic_fetch_add(root, 1u, __ATOMIC_RELAXED,
                                           __HIP_MEMORY_SCOPE_AGENT);
                const unsigned tgt = 4u * (unsigned)(s + 1);
                while (__hip_atomic_load(root, __ATOMIC_RELAXED,
                                         __HIP_MEMORY_SCOPE_AGENT) < tgt)
                    __builtin_amdgcn_s_sleep(1);
            }
            __syncthreads();
        }
    }
}

// ---------------------------------------------------------------------------
// Attention logits: logits[b][t] += sum_n tanh(hidden[t,b,:]·fcw[n,:] + fcb[n]) * upw[n]
// ---------------------------------------------------------------------------
__global__ __launch_bounds__(256) void attn_logits(
    const float* __restrict__ Xh,   // hidden [T*B][768]
    const float* __restrict__ fcw,  // [768][768]
    const float* __restrict__ fcb, const float* __restrict__ upw,
    float* __restrict__ logits)     // [B][T]
{
    __shared__ float As[BK][TILE + 4];
    __shared__ float Bs[BK][TILE + 4];
    __shared__ float red[TILE][17];
    const int tid = threadIdx.x;
    const int tx = tid & 15, ty = tid >> 4;
    const int m0 = blockIdx.y * TILE;
    const int n0 = blockIdx.x * TILE;

    float acc[8][8];
#pragma unroll
    for (int i = 0; i < 8; i++)
#pragma unroll
        for (int j = 0; j < 8; j++) acc[i][j] = 0.f;

    for (int k0 = 0; k0 < 768; k0 += BK) {
#pragma unroll
        for (int l = 0; l < 2; l++) {
            int id = tid + l * 256;
            int r  = id >> 2;
            int kq = (id & 3) * 4;
            float4 v = *(const float4*)(Xh + (size_t)(m0 + r) * 768 + k0 + kq);
            As[kq + 0][r] = v.x; As[kq + 1][r] = v.y;
            As[kq + 2][r] = v.z; As[kq + 3][r] = v.w;
        }
#pragma unroll
        for (int l = 0; l < 2; l++) {
            int id = tid + l * 256;
            int r  = id >> 2;
            int kq = (id & 3) * 4;
            float4 v = *(const float4*)(fcw + (size_t)(n0 + r) * 768 + k0 + kq);
            Bs[kq + 0][r] = v.x; Bs[kq + 1][r] = v.y;
            Bs[kq + 2][r] = v.z; Bs[kq + 3][r] = v.w;
        }
        __syncthreads();
#pragma unroll
        for (int kk = 0; kk < BK; ++kk) {
            float av[8], bv[8];
            *(float4*)&av[0] = *(const float4*)&As[kk][ty * 8];
            *(float4*)&av[4] = *(const float4*)&As[kk][ty * 8 + 4];
            *(float4*)&bv[0] = *(const float4*)&Bs[kk][tx * 8];
            *(float4*)&bv[4] = *(const float4*)&Bs[kk][tx * 8 + 4];
#pragma unroll
            for (int i = 0; i < 8; i++)
#pragma unroll
                for (int j = 0; j < 8; j++)
                    acc[i][j] = fmaf(av[i], bv[j], acc[i][j]);
        }
        __syncthreads();
    }

#pragma unroll
    for (int i = 0; i < 8; i++) {
        float p = 0.f;
#pragma unroll
        for (int jj = 0; jj < 8; jj++) {
            int n = n0 + tx * 8 + jj;
            p += tanhf(acc[i][jj] + fcb[n]) * upw[n];
        }
        red[ty * 8 + i][tx] = p;
    }
    __syncthreads();
    if (tid < TILE) {
        float s = 0.f;
#pragma unroll
        for (int x = 0; x < 16; x++) s += red[tid][x];
        int m = m0 + tid;
        int t = m >> 6, b = m & 63;
        atomicAdd(&logits[(size_t)b * TT + t], s);
    }
}

// ---------------------------------------------------------------------------
// Softmax over T per batch + weighted pooling
// ---------------------------------------------------------------------------
__global__ __launch_bounds__(256) void softmax_pool(
    const float* __restrict__ logits, const float* __restrict__ upwb,
    const float* __restrict__ hidden, float* __restrict__ out)
{
    const int b = blockIdx.x, tid = threadIdx.x;
    __shared__ float sa[256];
    __shared__ float red[256];

    float l = logits[(size_t)b * TT + tid] + upwb[0];
    red[tid] = l; __syncthreads();
    for (int s = 128; s > 0; s >>= 1) {
        if (tid < s) red[tid] = fmaxf(red[tid], red[tid + s]);
        __syncthreads();
    }
    float mx = red[0];
    __syncthreads();
    float e = expf(l - mx);
    sa[tid] = e; red[tid] = e; __syncthreads();
    for (int s = 128; s > 0; s >>= 1) {
        if (tid < s) red[tid] += red[tid + s];
        __syncthreads();
    }
    float inv = 1.f / red[0];

    float o0 = 0.f, o1 = 0.f, o2 = 0.f;
    for (int t = 0; t < TT; t++) {
        float a = sa[t] * inv;
        const float* hp = hidden + (size_t)t * (BB * DD) + (size_t)b * DD;
        o0 = fmaf(a, hp[tid],       o0);
        o1 = fmaf(a, hp[tid + 256], o1);
        o2 = fmaf(a, hp[tid + 512], o2);
    }
    out[(size_t)b * DD + tid]       = o0;
    out[(size_t)b * DD + tid + 256] = o1;
    out[(size_t)b * DD + tid + 512] = o2;
}

// ---------------------------------------------------------------------------
extern "C" void kernel_launch(void* const* d_in, const int* in_sizes, int n_in,
                              void* d_out, int out_size, void* d_ws, size_t ws_size,
                              hipStream_t stream)
{
    const float* S        = (const float*)d_in[0];
    const float* w_ih_l0f = (const float*)d_in[1];
    const float* w_hh_l0f = (const float*)d_in[2];
    const float* b_ih_l0f = (const float*)d_in[3];
    const float* b_hh_l0f = (const float*)d_in[4];
    const float* w_ih_l0b = (const float*)d_in[5];
    const float* w_hh_l0b = (const float*)d_in[6];
    const float* b_ih_l0b = (const float*)d_in[7];
    const float* b_hh_l0b = (const float*)d_in[8];
    const float* w_ih_l1f = (const float*)d_in[9];
    const float* w_hh_l1f = (const float*)d_in[10];
    const float* b_ih_l1f = (const float*)d_in[11];
    const float* b_hh_l1f = (const float*)d_in[12];
    const float* w_ih_l1b = (const float*)d_in[13];
    const float* w_hh_l1b = (const float*)d_in[14];
    const float* b_ih_l1b = (const float*)d_in[15];
    const float* b_hh_l1b = (const float*)d_in[16];
    const float* fc_w     = (const float*)d_in[17];
    const float* fc_b     = (const float*)d_in[18];
    const float* upw_w    = (const float*)d_in[19];
    const float* upw_b    = (const float*)d_in[20];

    // workspace layout (floats)
    float* gxT    = (float*)d_ws;                       // 256*2304*64
    float* buf2   = gxT  + (size_t)TT * G6 * BB;        // 256*64*768
    float* hbuf   = buf2 + (size_t)TT * BB * DD;        // 2*2*96*64*4 = 98304
    float* logits = hbuf + (size_t)98304;               // 64*256      = 16384
    unsigned* cnt = (unsigned*)(logits + 16384);        // 32 barrier counters

    const size_t LDSZ = (4 * 96 * 64 + 4 * 9 * 64) * sizeof(float);  // 107520

    // zero h ping-pong + logits + counters (contiguous region)
    hipMemsetAsync(hbuf, 0, (size_t)(98304 + 16384) * sizeof(float) + 128, stream);

    // layer 0 input gates
    gemm_gx<<<dim3(18, 128), 256, 0, stream>>>(S, 0, w_ih_l0f, w_ih_l0b,
                                               b_ih_l0f, b_ih_l0b, gxT);
    // layer 0 recurrence -> buf2
    {
        unsigned* c0 = cnt;
        void* args[] = {(void*)&gxT, (void*)&w_hh_l0f, (void*)&w_hh_l0b,
                        (void*)&b_hh_l0f, (void*)&b_hh_l0b, (void*)&hbuf,
                        (void*)&buf2, (void*)&c0};
        hipLaunchCooperativeKernel((const void*)recur3, dim3(256), dim3(256),
                                   args, LDSZ, stream);
    }
    // re-zero h for layer 1 (layer-1 counters separate, still zero)
    hipMemsetAsync(hbuf, 0, (size_t)98304 * sizeof(float), stream);

    // layer 1 input gates (from buf2)
    gemm_gx<<<dim3(18, 128), 256, 0, stream>>>(buf2, 1, w_ih_l1f, w_ih_l1b,
                                               b_ih_l1f, b_ih_l1b, gxT);
    // layer 1 recurrence -> buf2 (overwrites; gx already materialized)
    {
        unsigned* c1 = cnt + 16;
        void* args[] = {(void*)&gxT, (void*)&w_hh_l1f, (void*)&w_hh_l1b,
                        (void*)&b_hh_l1f, (void*)&b_hh_l1b, (void*)&hbuf,
                        (void*)&buf2, (void*)&c1};
        hipLaunchCooperativeKernel((const void*)recur3, dim3(256), dim3(256),
                                   args, LDSZ, stream);
    }
    // attention logits + pooling
    attn_logits<<<dim3(6, 128), 256, 0, stream>>>(buf2, fc_w, fc_b, upw_w, logits);
    softmax_pool<<<64, 256, 0, stream>>>(logits, upw_b, buf2, (float*)d_out);
}

// Round 4
// 6380.996 us; speedup vs baseline: 2.4700x; 2.4700x over previous
//
#include <hip/hip_runtime.h>

// Problem constants
#define BB   64      // batch
#define TT   256     // seq len
#define II   768     // input dim
#define HH   384     // hidden per direction
#define DD   768     // 2*HH
#define G3   1152    // 3*HH
#define G6   2304    // both directions' gates

#define TILE 128
#define BK   16

typedef unsigned long long u64t;
typedef __attribute__((ext_vector_type(4))) unsigned int u32x4;

// ---------------------------------------------------------------------------
// GEMM: gxT[t][n][b] = bias[n] + sum_k X[t,b,k] * W[n,k]   (n in [0,2304))
// Transposed output (n-major, batch-minor): recurrent kernel reads 256-B
// coalesced rows per (gate,col).
// ---------------------------------------------------------------------------
__global__ __launch_bounds__(256) void gemm_gx(
    const float* __restrict__ X, int xmode,
    const float* __restrict__ wf, const float* __restrict__ wb,
    const float* __restrict__ bif, const float* __restrict__ bib,
    float* __restrict__ gx)
{
    __shared__ float As[BK][TILE + 4];
    __shared__ float Bs[BK][TILE + 4];
    const int tid = threadIdx.x;
    const int tx = tid & 15, ty = tid >> 4;
    const int m0 = blockIdx.y * TILE;
    const int n0 = blockIdx.x * TILE;

    float acc[8][8];
#pragma unroll
    for (int i = 0; i < 8; i++)
#pragma unroll
        for (int j = 0; j < 8; j++) acc[i][j] = 0.f;

    for (int k0 = 0; k0 < 768; k0 += BK) {
#pragma unroll
        for (int l = 0; l < 2; l++) {
            int id = tid + l * 256;          // 0..511
            int r  = id >> 2;                // 0..127
            int kq = (id & 3) * 4;
            int m  = m0 + r;
            const float* src;
            if (xmode == 0) {
                int b = m & 63, t = m >> 6;
                src = X + (size_t)b * (TT * II) + (size_t)t * II + k0 + kq;
            } else {
                src = X + (size_t)m * 768 + k0 + kq;
            }
            float4 v = *(const float4*)src;
            As[kq + 0][r] = v.x; As[kq + 1][r] = v.y;
            As[kq + 2][r] = v.z; As[kq + 3][r] = v.w;
        }
#pragma unroll
        for (int l = 0; l < 2; l++) {
            int id = tid + l * 256;
            int r  = id >> 2;
            int kq = (id & 3) * 4;
            int n  = n0 + r;
            const float* wsrc = (n < G3) ? (wf + (size_t)n * 768)
                                         : (wb + (size_t)(n - G3) * 768);
            float4 v = *(const float4*)(wsrc + k0 + kq);
            Bs[kq + 0][r] = v.x; Bs[kq + 1][r] = v.y;
            Bs[kq + 2][r] = v.z; Bs[kq + 3][r] = v.w;
        }
        __syncthreads();
#pragma unroll
        for (int kk = 0; kk < BK; ++kk) {
            float av[8], bv[8];
            *(float4*)&av[0] = *(const float4*)&As[kk][ty * 8];
            *(float4*)&av[4] = *(const float4*)&As[kk][ty * 8 + 4];
            *(float4*)&bv[0] = *(const float4*)&Bs[kk][tx * 8];
            *(float4*)&bv[4] = *(const float4*)&Bs[kk][tx * 8 + 4];
#pragma unroll
            for (int i = 0; i < 8; i++)
#pragma unroll
                for (int j = 0; j < 8; j++)
                    acc[i][j] = fmaf(av[i], bv[j], acc[i][j]);
        }
        __syncthreads();
    }

#pragma unroll
    for (int i = 0; i < 8; i++) {
        int m = m0 + ty * 8 + i;
        int t = m >> 6, b = m & 63;
        float* dst = gx + ((size_t)t * G6 + n0 + tx * 8) * 64 + b;
#pragma unroll
        for (int j = 0; j < 8; j++) {
            int n = n0 + tx * 8 + j;
            float bias = (n < G3) ? bif[n] : bib[n - G3];
            dst[(size_t)j * 64] = acc[i][j] + bias;
        }
    }
}

// ---------------------------------------------------------------------------
// Recurrent kernel v5: BARRIER-FREE via self-tagged h exchange.
//
// h is stored as u64 pairs (fp32 value, u32 step-tag) in layout
// [kp=col/2][lane=b][2] (16 B per (kp,lane)); producers publish with one
// relaxed agent-scope u64 store (tag travels atomically with value -> no
// fence, no counter, no barrier). Consumers load their k-chunk straight
// into registers with inline-asm global_load_dwordx4 sc0 sc1 (bypass the
// possibly-stale local L1/L2; L3 is the coherence point) and retry a
// 12-load block until all tags == current step.
//
// 192 WGs x 256 thr: WG 0..95 forward, 96..191 backward; 4 columns per WG;
// wave w covers k-chunk [w*96,(w+1)*96) for all 12 (col,gate) dots, then
// finalizes column c0+w after an LDS partial reduce (double-buffered,
// ONE __syncthreads per step).
// ---------------------------------------------------------------------------
__global__ __launch_bounds__(256) void recur5(
    const float* __restrict__ gxT,  // [T][2304][64] (b_ih already added)
    const float* __restrict__ whf, const float* __restrict__ whb,
    const float* __restrict__ bhf, const float* __restrict__ bhb,
    u64t* __restrict__ hbuf,        // [2 dir][2 pp][192 kp][64][2] u64, zeroed
    float* __restrict__ out)        // [T][B][768]
{
    __shared__ float part[2][4][12][64];    // [pp][wave][col*3+gate][lane]

    const int bid  = blockIdx.x;            // 0..191
    const int dir  = bid / 96;
    const int c0   = (bid % 96) * 4;
    const int tid  = threadIdx.x;
    const int lane = tid & 63;              // batch
    const int w    = __builtin_amdgcn_readfirstlane(tid >> 6);  // wave 0..3
    const int c    = c0 + w;                // column this wave finalizes

    const float* wh = dir ? whb : whf;
    const float* bh = dir ? bhb : bhf;

    // 12 uniform weight row pointers, offset to this wave's k-chunk
    const float* wpp[12];
#pragma unroll
    for (int cc = 0; cc < 4; cc++)
#pragma unroll
        for (int g = 0; g < 3; g++)
            wpp[cc * 3 + g] = wh + (size_t)(g * HH + c0 + cc) * HH + w * 96;

    const float bhr = bh[c], bhz = bh[HH + c], bhn = bh[2 * HH + c];

    u64t* hb = hbuf + (size_t)dir * 2 * (192 * 64 * 2);
    const unsigned va0 = (unsigned)(lane * 16);
    const unsigned va1 = va0 + 4096;
    const unsigned va2 = va0 + 8192;

    float hprev = 0.f;

    for (int s = 0; s < TT; s++) {
        const int t = dir ? (TT - 1 - s) : s;
        const u64t* hcur = hb + (size_t)(s & 1) * (192 * 64 * 2);
        u64t*       hnxt = hb + (size_t)((s & 1) ^ 1) * (192 * 64 * 2);
        const unsigned want = (unsigned)s;

        // gx loads for my column: issued now, consumed at step end
        const float* g0 = gxT + ((size_t)t * G6 + dir * G3) * 64;
        float gr = g0[(size_t)(0 * HH + c) * 64 + lane];
        float gz = g0[(size_t)(1 * HH + c) * 64 + lane];
        float gn = g0[(size_t)(2 * HH + c) * 64 + lane];

        float acc[12];
#pragma unroll
        for (int i = 0; i < 12; i++) acc[i] = 0.f;

        // 4 blocks of 12 dwordx4 (= 24 k-values each)
#pragma unroll 1
        for (int blk = 0; blk < 4; blk++) {
            const u64t* bp = hcur + (size_t)(w * 48 + blk * 12) * 128;
            unsigned long long base = (unsigned long long)bp;
            u32x4 r[12];

            while (true) {
                asm volatile(
                    "global_load_dwordx4 %0, %12, %15 sc0 sc1\n\t"
                    "global_load_dwordx4 %1, %12, %15 offset:1024 sc0 sc1\n\t"
                    "global_load_dwordx4 %2, %12, %15 offset:2048 sc0 sc1\n\t"
                    "global_load_dwordx4 %3, %12, %15 offset:3072 sc0 sc1\n\t"
                    "global_load_dwordx4 %4, %13, %15 sc0 sc1\n\t"
                    "global_load_dwordx4 %5, %13, %15 offset:1024 sc0 sc1\n\t"
                    "global_load_dwordx4 %6, %13, %15 offset:2048 sc0 sc1\n\t"
                    "global_load_dwordx4 %7, %13, %15 offset:3072 sc0 sc1\n\t"
                    "global_load_dwordx4 %8, %14, %15 sc0 sc1\n\t"
                    "global_load_dwordx4 %9, %14, %15 offset:1024 sc0 sc1\n\t"
                    "global_load_dwordx4 %10, %14, %15 offset:2048 sc0 sc1\n\t"
                    "global_load_dwordx4 %11, %14, %15 offset:3072 sc0 sc1\n\t"
                    "s_waitcnt vmcnt(0)"
                    : "=&v"(r[0]), "=&v"(r[1]), "=&v"(r[2]), "=&v"(r[3]),
                      "=&v"(r[4]), "=&v"(r[5]), "=&v"(r[6]), "=&v"(r[7]),
                      "=&v"(r[8]), "=&v"(r[9]), "=&v"(r[10]), "=&v"(r[11])
                    : "v"(va0), "v"(va1), "v"(va2), "s"(base)
                    : "memory");

                bool ok = true;
#pragma unroll
                for (int jj = 0; jj < 12; jj++)
                    ok = ok && (r[jj].y == want) && (r[jj].w == want);
                if (__all(ok)) break;
                __builtin_amdgcn_s_sleep(1);
            }

#pragma unroll
            for (int jj = 0; jj < 12; jj++) {
                float v0 = __uint_as_float(r[jj].x);
                float v1 = __uint_as_float(r[jj].z);
                const int ko = blk * 24 + jj * 2;
#pragma unroll
                for (int cg = 0; cg < 12; cg++) {
                    acc[cg] = fmaf(v0, wpp[cg][ko],     acc[cg]);
                    acc[cg] = fmaf(v1, wpp[cg][ko + 1], acc[cg]);
                }
            }
        }

        // partial reduce through LDS (double-buffered, one barrier/step)
#pragma unroll
        for (int cg = 0; cg < 12; cg++)
            part[s & 1][w][cg][lane] = acc[cg];
        __syncthreads();

        const int d0 = w * 3;
        float ar = part[s & 1][0][d0 + 0][lane] + part[s & 1][1][d0 + 0][lane]
                 + part[s & 1][2][d0 + 0][lane] + part[s & 1][3][d0 + 0][lane];
        float az = part[s & 1][0][d0 + 1][lane] + part[s & 1][1][d0 + 1][lane]
                 + part[s & 1][2][d0 + 1][lane] + part[s & 1][3][d0 + 1][lane];
        float an = part[s & 1][0][d0 + 2][lane] + part[s & 1][1][d0 + 2][lane]
                 + part[s & 1][2][d0 + 2][lane] + part[s & 1][3][d0 + 2][lane];

        float ghr = ar + bhr, ghz = az + bhz, ghn = an + bhn;
        float rr  = 1.f / (1.f + expf(-(gr + ghr)));
        float zz  = 1.f / (1.f + expf(-(gz + ghz)));
        float nn  = tanhf(gn + rr * ghn);
        float hnew = (1.f - zz) * nn + zz * hprev;
        hprev = hnew;

        // publish (value, tag) atomically; tag = s+1
        u64t pv = ((u64t)(unsigned)(s + 1) << 32) | (u64t)__float_as_uint(hnew);
        __hip_atomic_store(hnxt + (size_t)(c >> 1) * 128 + lane * 2 + (c & 1),
                           pv, __ATOMIC_RELAXED, __HIP_MEMORY_SCOPE_AGENT);
        // big output tensor: normal store
        out[(size_t)t * (BB * DD) + (size_t)lane * DD + dir * HH + c] = hnew;
    }
}

// ---------------------------------------------------------------------------
// Attention logits: logits[b][t] += sum_n tanh(hidden[t,b,:]·fcw[n,:] + fcb[n]) * upw[n]
// ---------------------------------------------------------------------------
__global__ __launch_bounds__(256) void attn_logits(
    const float* __restrict__ Xh,   // hidden [T*B][768]
    const float* __restrict__ fcw,  // [768][768]
    const float* __restrict__ fcb, const float* __restrict__ upw,
    float* __restrict__ logits)     // [B][T]
{
    __shared__ float As[BK][TILE + 4];
    __shared__ float Bs[BK][TILE + 4];
    __shared__ float red[TILE][17];
    const int tid = threadIdx.x;
    const int tx = tid & 15, ty = tid >> 4;
    const int m0 = blockIdx.y * TILE;
    const int n0 = blockIdx.x * TILE;

    float acc[8][8];
#pragma unroll
    for (int i = 0; i < 8; i++)
#pragma unroll
        for (int j = 0; j < 8; j++) acc[i][j] = 0.f;

    for (int k0 = 0; k0 < 768; k0 += BK) {
#pragma unroll
        for (int l = 0; l < 2; l++) {
            int id = tid + l * 256;
            int r  = id >> 2;
            int kq = (id & 3) * 4;
            float4 v = *(const float4*)(Xh + (size_t)(m0 + r) * 768 + k0 + kq);
            As[kq + 0][r] = v.x; As[kq + 1][r] = v.y;
            As[kq + 2][r] = v.z; As[kq + 3][r] = v.w;
        }
#pragma unroll
        for (int l = 0; l < 2; l++) {
            int id = tid + l * 256;
            int r  = id >> 2;
            int kq = (id & 3) * 4;
            float4 v = *(const float4*)(fcw + (size_t)(n0 + r) * 768 + k0 + kq);
            Bs[kq + 0][r] = v.x; Bs[kq + 1][r] = v.y;
            Bs[kq + 2][r] = v.z; Bs[kq + 3][r] = v.w;
        }
        __syncthreads();
#pragma unroll
        for (int kk = 0; kk < BK; ++kk) {
            float av[8], bv[8];
            *(float4*)&av[0] = *(const float4*)&As[kk][ty * 8];
            *(float4*)&av[4] = *(const float4*)&As[kk][ty * 8 + 4];
            *(float4*)&bv[0] = *(const float4*)&Bs[kk][tx * 8];
            *(float4*)&bv[4] = *(const float4*)&Bs[kk][tx * 8 + 4];
#pragma unroll
            for (int i = 0; i < 8; i++)
#pragma unroll
                for (int j = 0; j < 8; j++)
                    acc[i][j] = fmaf(av[i], bv[j], acc[i][j]);
        }
        __syncthreads();
    }

#pragma unroll
    for (int i = 0; i < 8; i++) {
        float p = 0.f;
#pragma unroll
        for (int jj = 0; jj < 8; jj++) {
            int n = n0 + tx * 8 + jj;
            p += tanhf(acc[i][jj] + fcb[n]) * upw[n];
        }
        red[ty * 8 + i][tx] = p;
    }
    __syncthreads();
    if (tid < TILE) {
        float s = 0.f;
#pragma unroll
        for (int x = 0; x < 16; x++) s += red[tid][x];
        int m = m0 + tid;
        int t = m >> 6, b = m & 63;
        atomicAdd(&logits[(size_t)b * TT + t], s);
    }
}

// ---------------------------------------------------------------------------
// Softmax over T per batch + weighted pooling
// ---------------------------------------------------------------------------
__global__ __launch_bounds__(256) void softmax_pool(
    const float* __restrict__ logits, const float* __restrict__ upwb,
    const float* __restrict__ hidden, float* __restrict__ out)
{
    const int b = blockIdx.x, tid = threadIdx.x;
    __shared__ float sa[256];
    __shared__ float red[256];

    float l = logits[(size_t)b * TT + tid] + upwb[0];
    red[tid] = l; __syncthreads();
    for (int s = 128; s > 0; s >>= 1) {
        if (tid < s) red[tid] = fmaxf(red[tid], red[tid + s]);
        __syncthreads();
    }
    float mx = red[0];
    __syncthreads();
    float e = expf(l - mx);
    sa[tid] = e; red[tid] = e; __syncthreads();
    for (int s = 128; s > 0; s >>= 1) {
        if (tid < s) red[tid] += red[tid + s];
        __syncthreads();
    }
    float inv = 1.f / red[0];

    float o0 = 0.f, o1 = 0.f, o2 = 0.f;
    for (int t = 0; t < TT; t++) {
        float a = sa[t] * inv;
        const float* hp = hidden + (size_t)t * (BB * DD) + (size_t)b * DD;
        o0 = fmaf(a, hp[tid],       o0);
        o1 = fmaf(a, hp[tid + 256], o1);
        o2 = fmaf(a, hp[tid + 512], o2);
    }
    out[(size_t)b * DD + tid]       = o0;
    out[(size_t)b * DD + tid + 256] = o1;
    out[(size_t)b * DD + tid + 512] = o2;
}

// ---------------------------------------------------------------------------
extern "C" void kernel_launch(void* const* d_in, const int* in_sizes, int n_in,
                              void* d_out, int out_size, void* d_ws, size_t ws_size,
                              hipStream_t stream)
{
    const float* S        = (const float*)d_in[0];
    const float* w_ih_l0f = (const float*)d_in[1];
    const float* w_hh_l0f = (const float*)d_in[2];
    const float* b_ih_l0f = (const float*)d_in[3];
    const float* b_hh_l0f = (const float*)d_in[4];
    const float* w_ih_l0b = (const float*)d_in[5];
    const float* w_hh_l0b = (const float*)d_in[6];
    const float* b_ih_l0b = (const float*)d_in[7];
    const float* b_hh_l0b = (const float*)d_in[8];
    const float* w_ih_l1f = (const float*)d_in[9];
    const float* w_hh_l1f = (const float*)d_in[10];
    const float* b_ih_l1f = (const float*)d_in[11];
    const float* b_hh_l1f = (const float*)d_in[12];
    const float* w_ih_l1b = (const float*)d_in[13];
    const float* w_hh_l1b = (const float*)d_in[14];
    const float* b_ih_l1b = (const float*)d_in[15];
    const float* b_hh_l1b = (const float*)d_in[16];
    const float* fc_w     = (const float*)d_in[17];
    const float* fc_b     = (const float*)d_in[18];
    const float* upw_w    = (const float*)d_in[19];
    const float* upw_b    = (const float*)d_in[20];

    // workspace layout (floats)
    float* gxT    = (float*)d_ws;                       // 256*2304*64
    float* buf2   = gxT  + (size_t)TT * G6 * BB;        // 256*64*768
    float* hbuf   = buf2 + (size_t)TT * BB * DD;        // 2*2*192*64*2 u64 = 196608 f
    float* logits = hbuf + (size_t)196608;              // 64*256 = 16384

    // zero h tag-buffers + logits (contiguous region)
    hipMemsetAsync(hbuf, 0, (size_t)(196608 + 16384) * sizeof(float), stream);

    // layer 0 input gates
    gemm_gx<<<dim3(18, 128), 256, 0, stream>>>(S, 0, w_ih_l0f, w_ih_l0b,
                                               b_ih_l0f, b_ih_l0b, gxT);
    // layer 0 recurrence -> buf2
    {
        u64t* hb = (u64t*)hbuf;
        void* args[] = {(void*)&gxT, (void*)&w_hh_l0f, (void*)&w_hh_l0b,
                        (void*)&b_hh_l0f, (void*)&b_hh_l0b, (void*)&hb,
                        (void*)&buf2};
        hipLaunchCooperativeKernel((const void*)recur5, dim3(192), dim3(256),
                                   args, 0, stream);
    }
    // re-zero tags for layer 1
    hipMemsetAsync(hbuf, 0, (size_t)196608 * sizeof(float), stream);

    // layer 1 input gates (from buf2)
    gemm_gx<<<dim3(18, 128), 256, 0, stream>>>(buf2, 1, w_ih_l1f, w_ih_l1b,
                                               b_ih_l1f, b_ih_l1b, gxT);
    // layer 1 recurrence -> buf2
    {
        u64t* hb = (u64t*)hbuf;
        void* args[] = {(void*)&gxT, (void*)&w_hh_l1f, (void*)&w_hh_l1b,
                        (void*)&b_hh_l1f, (void*)&b_hh_l1b, (void*)&hb,
                        (void*)&buf2};
        hipLaunchCooperativeKernel((const void*)recur5, dim3(192), dim3(256),
                                   args, 0, stream);
    }
    // attention logits + pooling
    attn_logits<<<dim3(6, 128), 256, 0, stream>>>(buf2, fc_w, fc_b, upw_w, logits);
    softmax_pool<<<64, 256, 0, stream>>>(logits, upw_b, buf2, (float*)d_out);
}